// Round 5
// baseline (670.318 us; speedup 1.0000x reference)
//
#include <hip/hip_runtime.h>
#include <stdint.h>

#define NB 8
#define NP 196
#define NM 2048
#define NH 768
#define NT 64

// ---------------- K1: mlo[row,c] = fm[row,:]·Wmap[c,:] + bmap[c], 8 rows/block
__global__ __launch_bounds__(256)
void k1_map(const float* __restrict__ fm, const float* __restrict__ Wmap,
            const float* __restrict__ bmap, float* __restrict__ mlo)
{
    __shared__ float s_fm[8][NM];                 // 64 KB
    const int row0 = blockIdx.x*8;
    for (int i=threadIdx.x; i<8*NM; i+=256){
        int r=i>>11, k=i&2047;
        s_fm[r][k] = fm[(size_t)(row0+r)*NM + k];
    }
    __syncthreads();
    #pragma unroll
    for (int it=0; it<3; ++it){
        int c = threadIdx.x + it*256;
        float acc[8];
        #pragma unroll
        for(int r=0;r<8;++r) acc[r]=0.f;
        const float* wr = Wmap + (size_t)c*NM;
        for (int k=0;k<NM;k+=4){
            float4 w4 = *(const float4*)(wr + k);
            #pragma unroll
            for(int r=0;r<8;++r){
                acc[r]=fmaf(w4.x,s_fm[r][k+0],acc[r]);
                acc[r]=fmaf(w4.y,s_fm[r][k+1],acc[r]);
                acc[r]=fmaf(w4.z,s_fm[r][k+2],acc[r]);
                acc[r]=fmaf(w4.w,s_fm[r][k+3],acc[r]);
            }
        }
        float bb = bmap[c];
        for(int r=0;r<8;++r) mlo[(size_t)(row0+r)*NH + c] = acc[r]+bb;
    }
}

// ---------------- K2: scores + softmax; one wave per t, 4 t per block
__global__ __launch_bounds__(256)
void k2_scores(const float* __restrict__ mlo, const float* __restrict__ hid,
               const float* __restrict__ Wrect, const float* __restrict__ brect,
               float* __restrict__ attn_out)   // fp32, (B,T,P) in d_out chunk 1
{
    const int b    = blockIdx.x >> 4;
    const int tg   = blockIdx.x & 15;
    const int wave = threadIdx.x >> 6;
    const int lane = threadIdx.x & 63;
    const int t    = tg*4 + wave;

    float hv[12], wv[12];
    #pragma unroll
    for (int j=0;j<12;++j){
        int h = lane + 64*j;
        hv[j] = hid[(size_t)(b*NT+t)*NH + h];
        wv[j] = Wrect[h];
    }
    __shared__ float s_sc[4][NP];
    for (int p=0;p<NP;++p){
        const float* mr = mlo + ((size_t)b*NP + p)*NH;
        float acc = 0.f;
        #pragma unroll
        for (int j=0;j<12;++j){
            float v = mr[lane+64*j] + hv[j];
            v = fmaxf(v,0.f);
            acc = fmaf(v,wv[j],acc);
        }
        #pragma unroll
        for (int off=32; off>0; off>>=1) acc += __shfl_down(acc,off);
        if (lane==0) s_sc[wave][p] = acc;
    }
    __syncthreads();

    const float br = brect[0];
    float x[4]; int pidx[4];
    #pragma unroll
    for (int i=0;i<4;++i){
        int p = lane + 64*i; pidx[i]=p;
        x[i] = (p<NP) ? (s_sc[wave][p] + br) : -3.0e38f;
    }
    float mx = fmaxf(fmaxf(x[0],x[1]),fmaxf(x[2],x[3]));
    #pragma unroll
    for (int off=32; off>0; off>>=1) mx = fmaxf(mx,__shfl_xor(mx,off));
    float sum=0.f;
    #pragma unroll
    for (int i=0;i<4;++i){
        x[i] = (pidx[i]<NP) ? __expf(x[i]-mx) : 0.f;
        sum += x[i];
    }
    #pragma unroll
    for (int off=32; off>0; off>>=1) sum += __shfl_xor(sum,off);
    const float inv = 1.f/sum;
    const size_t base = (size_t)(b*NT+t)*NP;
    #pragma unroll
    for (int i=0;i<4;++i){
        if (pidx[i]<NP) attn_out[base+pidx[i]] = x[i]*inv;
    }
}

// ---------------- K3: ctx[b,t,m] = sum_p attn[b,t,p]*fm[b,p,m]; 4 t per block
__global__ __launch_bounds__(256)
void k3_ctx(const float* __restrict__ attn, const float* __restrict__ fm,
            float* __restrict__ ctx)
{
    const int b  = blockIdx.x >> 4;
    const int tg = blockIdx.x & 15;
    __shared__ float s_a[4][NP];
    for (int i=threadIdx.x; i<4*NP; i+=256){
        int tt=i/NP, p=i-tt*NP;
        s_a[tt][p] = attn[(size_t)(b*NT + tg*4+tt)*NP + p];
    }
    __syncthreads();
    const int m0 = threadIdx.x*8;
    float acc[4][8];
    #pragma unroll
    for(int tt=0;tt<4;++tt)
        #pragma unroll
        for(int i=0;i<8;++i) acc[tt][i]=0.f;
    const float* fb = fm + (size_t)b*NP*NM + m0;
    for (int p=0;p<NP;++p){
        float4 u0 = *(const float4*)(fb + (size_t)p*NM);
        float4 u1 = *(const float4*)(fb + (size_t)p*NM + 4);
        float f[8] = {u0.x,u0.y,u0.z,u0.w,u1.x,u1.y,u1.z,u1.w};
        #pragma unroll
        for(int tt=0;tt<4;++tt){
            float a = s_a[tt][p];
            #pragma unroll
            for(int i=0;i<8;++i) acc[tt][i] = fmaf(a,f[i],acc[tt][i]);
        }
    }
    #pragma unroll
    for(int tt=0;tt<4;++tt){
        float* cr = ctx + (size_t)(b*NT + tg*4+tt)*NM + m0;
        #pragma unroll
        for(int i=0;i<8;++i) cr[i]=acc[tt][i];
    }
}

// ---------------- K4: out[row,c] = ctx[row,:]·Wfin[c,:] + bfin[c] + hid[row,c]; 8 rows/block
__global__ __launch_bounds__(256)
void k4_final(const float* __restrict__ ctx, const float* __restrict__ Wfin,
              const float* __restrict__ bfin, const float* __restrict__ hid,
              float* __restrict__ out)
{
    __shared__ float s_c[8][NM];                  // 64 KB
    const int row0 = blockIdx.x*8;
    for (int i=threadIdx.x; i<8*NM; i+=256){
        int r=i>>11, k=i&2047;
        s_c[r][k] = ctx[(size_t)(row0+r)*NM + k];
    }
    __syncthreads();
    #pragma unroll
    for (int it=0; it<3; ++it){
        int c = threadIdx.x + it*256;
        float acc[8];
        #pragma unroll
        for(int r=0;r<8;++r) acc[r]=0.f;
        const float* wr = Wfin + (size_t)c*NM;
        for (int k=0;k<NM;k+=4){
            float4 w4 = *(const float4*)(wr + k);
            #pragma unroll
            for(int r=0;r<8;++r){
                acc[r]=fmaf(w4.x,s_c[r][k+0],acc[r]);
                acc[r]=fmaf(w4.y,s_c[r][k+1],acc[r]);
                acc[r]=fmaf(w4.z,s_c[r][k+2],acc[r]);
                acc[r]=fmaf(w4.w,s_c[r][k+3],acc[r]);
            }
        }
        float bb = bfin[c];
        for(int r=0;r<8;++r){
            out[(size_t)(row0+r)*NH + c] =
                acc[r] + bb + hid[(size_t)(row0+r)*NH + c];
        }
    }
}

extern "C" void kernel_launch(void* const* d_in, const int* in_sizes, int n_in,
                              void* d_out, int out_size, void* d_ws, size_t ws_size,
                              hipStream_t stream)
{
    // Inputs: fp32, setup_inputs() dict order (confirmed R2==R4 bit-identical).
    const float* maps  = (const float*)d_in[0];
    const float* hid   = (const float*)d_in[1];
    const float* Wmap  = (const float*)d_in[2];
    const float* bmap  = (const float*)d_in[3];
    const float* Wfin  = (const float*)d_in[4];
    const float* bfin  = (const float*)d_in[5];
    const float* Wrect = (const float*)d_in[6];
    const float* brect = (const float*)d_in[7];

    // Outputs: fp32 (reference returns fp32). chunk0 = out (B,T,H), chunk1 = attn (B,T,P).
    float* out_ptr  = (float*)d_out;
    float* attn_out = out_ptr + (size_t)NB*NT*NH;

    float* mlo = (float*)d_ws;                       // B*P*H fp32 = 4.82 MB
    float* ctx = mlo + (size_t)NB*NP*NH;             // B*T*M fp32 = 4.19 MB

    hipLaunchKernelGGL(k1_map,   dim3(NB*NP/8),   dim3(256), 0, stream, maps, Wmap, bmap, mlo);
    hipLaunchKernelGGL(k2_scores,dim3(NB*(NT/4)), dim3(256), 0, stream, mlo, hid, Wrect, brect, attn_out);
    hipLaunchKernelGGL(k3_ctx,   dim3(NB*(NT/4)), dim3(256), 0, stream, attn_out, maps, ctx);
    hipLaunchKernelGGL(k4_final, dim3(NB*NT/8),   dim3(256), 0, stream, ctx, Wfin, bfin, hid, out_ptr);
}

// Round 6
// 305.644 us; speedup vs baseline: 2.1931x; 2.1931x over previous
//
#include <hip/hip_runtime.h>
#include <stdint.h>

#define NB 8
#define NP 196
#define NM 2048
#define NH 768
#define NT 64

typedef __attribute__((ext_vector_type(8))) short short8;
typedef __attribute__((ext_vector_type(4))) float floatx4;

__device__ __forceinline__ float b2f_(uint16_t u){ union{uint32_t i; float f;} v; v.i=(uint32_t)u<<16; return v.f; }
__device__ __forceinline__ float lo2f_(uint32_t u){ union{uint32_t i; float f;} v; v.i=u<<16; return v.f; }
__device__ __forceinline__ float hi2f_(uint32_t u){ union{uint32_t i; float f;} v; v.i=u&0xffff0000u; return v.f; }
__device__ __forceinline__ uint16_t f2b_(float f){
    union{float f; uint32_t i;} v; v.f=f; uint32_t x=v.i;
    return (uint16_t)((x + 0x7fffu + ((x>>16)&1u))>>16);
}
__device__ __forceinline__ short8 ldfrag(const uint16_t* p){
    union{ uint4 u; short8 s; } v;
    v.u = *(const uint4*)p;
    return v.s;
}

// ---------- cvt3: fp32 -> bf16 for maps, W_map, W_final (one launch) ----------
__global__ __launch_bounds__(256)
void cvt3(const float* __restrict__ s0, uint16_t* __restrict__ d0, int n0,
          const float* __restrict__ s1, uint16_t* __restrict__ d1, int n1,
          const float* __restrict__ s2, uint16_t* __restrict__ d2, int n2)
{
    long i = (long)(blockIdx.x*256 + threadIdx.x)*8;
    const float* s; uint16_t* d; long j;
    if (i < n0)                { s=s0; d=d0; j=i; }
    else if (i < (long)n0+n1)  { s=s1; d=d1; j=i-n0; }
    else                       { s=s2; d=d2; j=i-n0-n1; if (j>=n2) return; }
    float4 a = *(const float4*)(s+j);
    float4 b = *(const float4*)(s+j+4);
    uint4 w;
    w.x = (uint32_t)f2b_(a.x) | ((uint32_t)f2b_(a.y)<<16);
    w.y = (uint32_t)f2b_(a.z) | ((uint32_t)f2b_(a.w)<<16);
    w.z = (uint32_t)f2b_(b.x) | ((uint32_t)f2b_(b.y)<<16);
    w.w = (uint32_t)f2b_(b.z) | ((uint32_t)f2b_(b.w)<<16);
    *(uint4*)(d+j) = w;
}

// ---------- K1 (MFMA): mlo[row,c] = fm·Wmap^T + bmap, bf16 in, bf16 out ----------
// wave-tile 64x64, one wave per block. A[m][k] frag: m=lane&15, k=quad*8+j.
__global__ __launch_bounds__(64)
void k1_mfma(const uint16_t* __restrict__ A, const uint16_t* __restrict__ Bw,
             const float* __restrict__ bias, uint16_t* __restrict__ mlo)
{
    const int lane = threadIdx.x;
    const int quad = lane>>4, lq = lane&15;
    const int row0 = blockIdx.x*64, n0 = blockIdx.y*64;
    const uint16_t* ap[4]; const uint16_t* bp[4];
    #pragma unroll
    for (int i=0;i<4;++i){
        int r = row0 + i*16 + lq; if (r > NB*NP-1) r = NB*NP-1;   // clamp loads, guard stores
        ap[i] = A  + (size_t)r*NM + quad*8;
        bp[i] = Bw + (size_t)(n0 + i*16 + lq)*NM + quad*8;
    }
    floatx4 acc[16];
    #pragma unroll
    for (int i=0;i<16;++i) acc[i] = (floatx4){0.f,0.f,0.f,0.f};

    short8 Aa[4],Ba[4],Ab[4],Bb[4];
    #pragma unroll
    for (int i=0;i<4;++i){ Aa[i]=ldfrag(ap[i]);    Ba[i]=ldfrag(bp[i]); }
    #pragma unroll
    for (int i=0;i<4;++i){ Ab[i]=ldfrag(ap[i]+32); Bb[i]=ldfrag(bp[i]+32); }

    for (int ks=0; ks<64; ks+=2){
        #pragma unroll
        for (int ms=0;ms<4;++ms)
            #pragma unroll
            for (int ns=0;ns<4;++ns)
                acc[ms*4+ns] = __builtin_amdgcn_mfma_f32_16x16x32_bf16(Aa[ms], Ba[ns], acc[ms*4+ns], 0,0,0);
        if (ks+2 < 64){
            const int off = (ks+2)*32;
            #pragma unroll
            for (int i=0;i<4;++i){ Aa[i]=ldfrag(ap[i]+off); Ba[i]=ldfrag(bp[i]+off); }
        }
        #pragma unroll
        for (int ms=0;ms<4;++ms)
            #pragma unroll
            for (int ns=0;ns<4;++ns)
                acc[ms*4+ns] = __builtin_amdgcn_mfma_f32_16x16x32_bf16(Ab[ms], Bb[ns], acc[ms*4+ns], 0,0,0);
        if (ks+3 < 64){
            const int off = (ks+3)*32;
            #pragma unroll
            for (int i=0;i<4;++i){ Ab[i]=ldfrag(ap[i]+off); Bb[i]=ldfrag(bp[i]+off); }
        }
    }
    // C/D: col=lane&15, row=quad*4+reg
    #pragma unroll
    for (int ns=0;ns<4;++ns){
        const int col = n0 + ns*16 + lq;
        const float bv = bias[col];
        #pragma unroll
        for (int ms=0;ms<4;++ms){
            floatx4 c = acc[ms*4+ns];
            const int rb = row0 + ms*16 + quad*4;
            #pragma unroll
            for (int r=0;r<4;++r){
                int row = rb + r;
                if (row < NB*NP) mlo[(size_t)row*NH + col] = f2b_(c[r] + bv);
            }
        }
    }
}

// ---------- K4 (MFMA): out[row,c] = ctx·Wfin^T + bfin + hid, fp32 out ----------
__global__ __launch_bounds__(64)
void k4_mfma(const uint16_t* __restrict__ A, const uint16_t* __restrict__ Bw,
             const float* __restrict__ bias, const float* __restrict__ hid,
             float* __restrict__ out)
{
    const int lane = threadIdx.x;
    const int quad = lane>>4, lq = lane&15;
    const int row0 = blockIdx.x*64, n0 = blockIdx.y*64;
    const uint16_t* ap[4]; const uint16_t* bp[4];
    #pragma unroll
    for (int i=0;i<4;++i){
        ap[i] = A  + (size_t)(row0 + i*16 + lq)*NM + quad*8;
        bp[i] = Bw + (size_t)(n0  + i*16 + lq)*NM + quad*8;
    }
    floatx4 acc[16];
    #pragma unroll
    for (int i=0;i<16;++i) acc[i] = (floatx4){0.f,0.f,0.f,0.f};

    short8 Aa[4],Ba[4],Ab[4],Bb[4];
    #pragma unroll
    for (int i=0;i<4;++i){ Aa[i]=ldfrag(ap[i]);    Ba[i]=ldfrag(bp[i]); }
    #pragma unroll
    for (int i=0;i<4;++i){ Ab[i]=ldfrag(ap[i]+32); Bb[i]=ldfrag(bp[i]+32); }

    for (int ks=0; ks<64; ks+=2){
        #pragma unroll
        for (int ms=0;ms<4;++ms)
            #pragma unroll
            for (int ns=0;ns<4;++ns)
                acc[ms*4+ns] = __builtin_amdgcn_mfma_f32_16x16x32_bf16(Aa[ms], Ba[ns], acc[ms*4+ns], 0,0,0);
        if (ks+2 < 64){
            const int off = (ks+2)*32;
            #pragma unroll
            for (int i=0;i<4;++i){ Aa[i]=ldfrag(ap[i]+off); Ba[i]=ldfrag(bp[i]+off); }
        }
        #pragma unroll
        for (int ms=0;ms<4;++ms)
            #pragma unroll
            for (int ns=0;ns<4;++ns)
                acc[ms*4+ns] = __builtin_amdgcn_mfma_f32_16x16x32_bf16(Ab[ms], Bb[ns], acc[ms*4+ns], 0,0,0);
        if (ks+3 < 64){
            const int off = (ks+3)*32;
            #pragma unroll
            for (int i=0;i<4;++i){ Ab[i]=ldfrag(ap[i]+off); Bb[i]=ldfrag(bp[i]+off); }
        }
    }
    #pragma unroll
    for (int ns=0;ns<4;++ns){
        const int col = n0 + ns*16 + lq;
        const float bv = bias[col];
        #pragma unroll
        for (int ms=0;ms<4;++ms){
            floatx4 c = acc[ms*4+ns];
            const int rb = row0 + ms*16 + quad*4;
            #pragma unroll
            for (int r=0;r<4;++r){
                const size_t idx = (size_t)(rb+r)*NH + col;
                out[idx] = c[r] + bv + hid[idx];
            }
        }
    }
}

// ---------- K2: scores + softmax; one wave per t, 4 t per block ----------
template<bool MB> __global__ __launch_bounds__(256)
void k2_scores(const void* __restrict__ mlo, const float* __restrict__ hid,
               const float* __restrict__ Wrect, const float* __restrict__ brect,
               float* __restrict__ attn_out)
{
    const int b    = blockIdx.x >> 4;
    const int tg   = blockIdx.x & 15;
    const int wave = threadIdx.x >> 6;
    const int lane = threadIdx.x & 63;
    const int t    = tg*4 + wave;

    float hv[12], wv[12];
    #pragma unroll
    for (int j=0;j<12;++j){
        int h = lane + 64*j;
        hv[j] = hid[(size_t)(b*NT+t)*NH + h];
        wv[j] = Wrect[h];
    }
    __shared__ float s_sc[4][NP];
    for (int p=0;p<NP;++p){
        const size_t mrow = ((size_t)b*NP + p)*NH;
        float acc = 0.f;
        #pragma unroll
        for (int j=0;j<12;++j){
            float m = MB ? b2f_(((const uint16_t*)mlo)[mrow + lane+64*j])
                         : ((const float*)mlo)[mrow + lane+64*j];
            float v = fmaxf(m + hv[j], 0.f);
            acc = fmaf(v,wv[j],acc);
        }
        #pragma unroll
        for (int off=32; off>0; off>>=1) acc += __shfl_down(acc,off);
        if (lane==0) s_sc[wave][p] = acc;
    }
    __syncthreads();

    const float br = brect[0];
    float x[4]; int pidx[4];
    #pragma unroll
    for (int i=0;i<4;++i){
        int p = lane + 64*i; pidx[i]=p;
        x[i] = (p<NP) ? (s_sc[wave][p] + br) : -3.0e38f;
    }
    float mx = fmaxf(fmaxf(x[0],x[1]),fmaxf(x[2],x[3]));
    #pragma unroll
    for (int off=32; off>0; off>>=1) mx = fmaxf(mx,__shfl_xor(mx,off));
    float sum=0.f;
    #pragma unroll
    for (int i=0;i<4;++i){
        x[i] = (pidx[i]<NP) ? __expf(x[i]-mx) : 0.f;
        sum += x[i];
    }
    #pragma unroll
    for (int off=32; off>0; off>>=1) sum += __shfl_xor(sum,off);
    const float inv = 1.f/sum;
    const size_t base = (size_t)(b*NT+t)*NP;
    #pragma unroll
    for (int i=0;i<4;++i){
        if (pidx[i]<NP) attn_out[base+pidx[i]] = x[i]*inv;
    }
}

// ---------- K3 (bf16): ctx_bf16[b,t,m] = sum_p attn*fm_bf16 ----------
__global__ __launch_bounds__(256)
void k3_ctxb(const float* __restrict__ attn, const uint16_t* __restrict__ fmb,
             uint16_t* __restrict__ ctxb)
{
    const int b  = blockIdx.x >> 4;
    const int tg = blockIdx.x & 15;
    __shared__ float s_a[4][NP];
    for (int i=threadIdx.x; i<4*NP; i+=256){
        int tt=i/NP, p=i-tt*NP;
        s_a[tt][p] = attn[(size_t)(b*NT + tg*4+tt)*NP + p];
    }
    __syncthreads();
    const int m0 = threadIdx.x*8;
    float acc[4][8];
    #pragma unroll
    for(int tt=0;tt<4;++tt)
        #pragma unroll
        for(int i=0;i<8;++i) acc[tt][i]=0.f;
    const uint16_t* fb = fmb + (size_t)b*NP*NM + m0;
    for (int p=0;p<NP;++p){
        uint4 u = *(const uint4*)(fb + (size_t)p*NM);
        float f[8] = {lo2f_(u.x),hi2f_(u.x),lo2f_(u.y),hi2f_(u.y),
                      lo2f_(u.z),hi2f_(u.z),lo2f_(u.w),hi2f_(u.w)};
        #pragma unroll
        for(int tt=0;tt<4;++tt){
            float a = s_a[tt][p];
            #pragma unroll
            for(int i=0;i<8;++i) acc[tt][i] = fmaf(a,f[i],acc[tt][i]);
        }
    }
    #pragma unroll
    for(int tt=0;tt<4;++tt){
        uint4 w;
        w.x = (uint32_t)f2b_(acc[tt][0]) | ((uint32_t)f2b_(acc[tt][1])<<16);
        w.y = (uint32_t)f2b_(acc[tt][2]) | ((uint32_t)f2b_(acc[tt][3])<<16);
        w.z = (uint32_t)f2b_(acc[tt][4]) | ((uint32_t)f2b_(acc[tt][5])<<16);
        w.w = (uint32_t)f2b_(acc[tt][6]) | ((uint32_t)f2b_(acc[tt][7])<<16);
        *(uint4*)(ctxb + (size_t)(b*NT + tg*4+tt)*NM + m0) = w;
    }
}

// =================== fallback (R5-proven fp32 path) ===================
__global__ __launch_bounds__(256)
void k1_map(const float* __restrict__ fm, const float* __restrict__ Wmap,
            const float* __restrict__ bmap, float* __restrict__ mlo)
{
    __shared__ float s_fm[8][NM];
    const int row0 = blockIdx.x*8;
    for (int i=threadIdx.x; i<8*NM; i+=256){
        int r=i>>11, k=i&2047;
        s_fm[r][k] = fm[(size_t)(row0+r)*NM + k];
    }
    __syncthreads();
    #pragma unroll
    for (int it=0; it<3; ++it){
        int c = threadIdx.x + it*256;
        float acc[8];
        #pragma unroll
        for(int r=0;r<8;++r) acc[r]=0.f;
        const float* wr = Wmap + (size_t)c*NM;
        for (int k=0;k<NM;k+=4){
            float4 w4 = *(const float4*)(wr + k);
            #pragma unroll
            for(int r=0;r<8;++r){
                acc[r]=fmaf(w4.x,s_fm[r][k+0],acc[r]);
                acc[r]=fmaf(w4.y,s_fm[r][k+1],acc[r]);
                acc[r]=fmaf(w4.z,s_fm[r][k+2],acc[r]);
                acc[r]=fmaf(w4.w,s_fm[r][k+3],acc[r]);
            }
        }
        float bb = bmap[c];
        for(int r=0;r<8;++r) mlo[(size_t)(row0+r)*NH + c] = acc[r]+bb;
    }
}

__global__ __launch_bounds__(256)
void k3_ctx(const float* __restrict__ attn, const float* __restrict__ fm,
            float* __restrict__ ctx)
{
    const int b  = blockIdx.x >> 4;
    const int tg = blockIdx.x & 15;
    __shared__ float s_a[4][NP];
    for (int i=threadIdx.x; i<4*NP; i+=256){
        int tt=i/NP, p=i-tt*NP;
        s_a[tt][p] = attn[(size_t)(b*NT + tg*4+tt)*NP + p];
    }
    __syncthreads();
    const int m0 = threadIdx.x*8;
    float acc[4][8];
    #pragma unroll
    for(int tt=0;tt<4;++tt)
        #pragma unroll
        for(int i=0;i<8;++i) acc[tt][i]=0.f;
    const float* fb = fm + (size_t)b*NP*NM + m0;
    for (int p=0;p<NP;++p){
        float4 u0 = *(const float4*)(fb + (size_t)p*NM);
        float4 u1 = *(const float4*)(fb + (size_t)p*NM + 4);
        float f[8] = {u0.x,u0.y,u0.z,u0.w,u1.x,u1.y,u1.z,u1.w};
        #pragma unroll
        for(int tt=0;tt<4;++tt){
            float a = s_a[tt][p];
            #pragma unroll
            for(int i=0;i<8;++i) acc[tt][i] = fmaf(a,f[i],acc[tt][i]);
        }
    }
    #pragma unroll
    for(int tt=0;tt<4;++tt){
        float* cr = ctx + (size_t)(b*NT + tg*4+tt)*NM + m0;
        #pragma unroll
        for(int i=0;i<8;++i) cr[i]=acc[tt][i];
    }
}

__global__ __launch_bounds__(256)
void k4_final(const float* __restrict__ ctx, const float* __restrict__ Wfin,
              const float* __restrict__ bfin, const float* __restrict__ hid,
              float* __restrict__ out)
{
    __shared__ float s_c[8][NM];
    const int row0 = blockIdx.x*8;
    for (int i=threadIdx.x; i<8*NM; i+=256){
        int r=i>>11, k=i&2047;
        s_c[r][k] = ctx[(size_t)(row0+r)*NM + k];
    }
    __syncthreads();
    #pragma unroll
    for (int it=0; it<3; ++it){
        int c = threadIdx.x + it*256;
        float acc[8];
        #pragma unroll
        for(int r=0;r<8;++r) acc[r]=0.f;
        const float* wr = Wfin + (size_t)c*NM;
        for (int k=0;k<NM;k+=4){
            float4 w4 = *(const float4*)(wr + k);
            #pragma unroll
            for(int r=0;r<8;++r){
                acc[r]=fmaf(w4.x,s_c[r][k+0],acc[r]);
                acc[r]=fmaf(w4.y,s_c[r][k+1],acc[r]);
                acc[r]=fmaf(w4.z,s_c[r][k+2],acc[r]);
                acc[r]=fmaf(w4.w,s_c[r][k+3],acc[r]);
            }
        }
        float bb = bfin[c];
        for(int r=0;r<8;++r){
            out[(size_t)(row0+r)*NH + c] =
                acc[r] + bb + hid[(size_t)(row0+r)*NH + c];
        }
    }
}

extern "C" void kernel_launch(void* const* d_in, const int* in_sizes, int n_in,
                              void* d_out, int out_size, void* d_ws, size_t ws_size,
                              hipStream_t stream)
{
    const float* maps  = (const float*)d_in[0];
    const float* hid   = (const float*)d_in[1];
    const float* Wmap  = (const float*)d_in[2];
    const float* bmap  = (const float*)d_in[3];
    const float* Wfin  = (const float*)d_in[4];
    const float* bfin  = (const float*)d_in[5];
    const float* Wrect = (const float*)d_in[6];
    const float* brect = (const float*)d_in[7];

    float* out_ptr  = (float*)d_out;                  // (B,T,H) fp32
    float* attn_out = out_ptr + (size_t)NB*NT*NH;     // (B,T,P) fp32

    const int    FME  = NB*NP*NM;                     // 3,211,264
    const int    WE   = NH*NM;                        // 1,572,864
    const size_t fmb_b  = (size_t)FME*2;              // 6,422,528
    const size_t w_b    = (size_t)WE*2;               // 3,145,728
    const size_t ctxb_b = (size_t)NB*NT*NM*2;         // 2,097,152
    const size_t mlob_b = (size_t)NB*NP*NH*2;         // 2,408,448
    const size_t need   = fmb_b + 2*w_b + ctxb_b + mlob_b;   // ~16.4 MB

    if (ws_size >= need) {
        uint16_t* fmb   = (uint16_t*)d_ws;
        uint16_t* wmapb = (uint16_t*)((char*)d_ws + fmb_b);
        uint16_t* wfinb = (uint16_t*)((char*)d_ws + fmb_b + w_b);
        uint16_t* ctxb  = (uint16_t*)((char*)d_ws + fmb_b + 2*w_b);
        uint16_t* mlob  = (uint16_t*)((char*)d_ws + fmb_b + 2*w_b + ctxb_b);

        const int total8 = (FME + 2*WE)/8;            // 794,624 threads
        hipLaunchKernelGGL(cvt3, dim3(total8/256), dim3(256), 0, stream,
                           maps, fmb, FME, Wmap, wmapb, WE, Wfin, wfinb, WE);
        hipLaunchKernelGGL(k1_mfma, dim3(25,12), dim3(64), 0, stream,
                           fmb, wmapb, bmap, mlob);
        hipLaunchKernelGGL((k2_scores<true>), dim3(NB*(NT/4)), dim3(256), 0, stream,
                           (const void*)mlob, hid, Wrect, brect, attn_out);
        hipLaunchKernelGGL(k3_ctxb, dim3(NB*(NT/4)), dim3(256), 0, stream,
                           attn_out, fmb, ctxb);
        hipLaunchKernelGGL(k4_mfma, dim3(8,12), dim3(64), 0, stream,
                           ctxb, wfinb, bfin, hid, out_ptr);
    } else {
        // R5-proven fp32 fallback
        float* mlo = (float*)d_ws;
        float* ctx = mlo + (size_t)NB*NP*NH;
        hipLaunchKernelGGL(k1_map,   dim3(NB*NP/8),   dim3(256), 0, stream, maps, Wmap, bmap, mlo);
        hipLaunchKernelGGL((k2_scores<false>), dim3(NB*(NT/4)), dim3(256), 0, stream,
                           (const void*)mlo, hid, Wrect, brect, attn_out);
        hipLaunchKernelGGL(k3_ctx,   dim3(NB*(NT/4)), dim3(256), 0, stream, attn_out, maps, ctx);
        hipLaunchKernelGGL(k4_final, dim3(NB*NT/8),   dim3(256), 0, stream, ctx, Wfin, bfin, hid, out_ptr);
    }
}

// Round 8
// 197.523 us; speedup vs baseline: 3.3936x; 1.5474x over previous
//
#include <hip/hip_runtime.h>
#include <stdint.h>

#define NB 8
#define NP 196
#define NM 2048
#define NH 768
#define NT 64
#define NHC 1536          // concat W_map ⊕ W_final rows
#define PPAD 224          // NP padded to multiple of 32 for MFMA K

typedef __attribute__((ext_vector_type(8))) short short8;
typedef __attribute__((ext_vector_type(4))) float floatx4;

__device__ __forceinline__ float lo2f_(uint32_t u){ union{uint32_t i; float f;} v; v.i=u<<16; return v.f; }
__device__ __forceinline__ float hi2f_(uint32_t u){ union{uint32_t i; float f;} v; v.i=u&0xffff0000u; return v.f; }
__device__ __forceinline__ uint16_t f2b_(float f){
    union{float f; uint32_t i;} v; v.f=f; uint32_t x=v.i;
    return (uint16_t)((x + 0x7fffu + ((x>>16)&1u))>>16);
}
__device__ __forceinline__ short8 ldfrag(const uint16_t* p){
    union{ uint4 u; short8 s; } v;
    v.u = *(const uint4*)p;
    return v.s;
}

// ---------- cvt3: fp32 -> bf16 for maps, W_map, W_final ----------
__global__ __launch_bounds__(256)
void cvt3(const float* __restrict__ s0, uint16_t* __restrict__ d0, int n0,
          const float* __restrict__ s1, uint16_t* __restrict__ d1, int n1,
          const float* __restrict__ s2, uint16_t* __restrict__ d2, int n2)
{
    long i = (long)(blockIdx.x*256 + threadIdx.x)*8;
    const float* s; uint16_t* d; long j;
    if (i < n0)                { s=s0; d=d0; j=i; }
    else if (i < (long)n0+n1)  { s=s1; d=d1; j=i-n0; }
    else                       { s=s2; d=d2; j=i-n0-n1; if (j>=n2) return; }
    float4 a = *(const float4*)(s+j);
    float4 b = *(const float4*)(s+j+4);
    uint4 w;
    w.x = (uint32_t)f2b_(a.x) | ((uint32_t)f2b_(a.y)<<16);
    w.y = (uint32_t)f2b_(a.z) | ((uint32_t)f2b_(a.w)<<16);
    w.z = (uint32_t)f2b_(b.x) | ((uint32_t)f2b_(b.y)<<16);
    w.w = (uint32_t)f2b_(b.z) | ((uint32_t)f2b_(b.w)<<16);
    *(uint4*)(d+j) = w;
}

// ---------- K1': [mlo | G] = fm · [Wmap;Wfin]^T. Wave-tile 32x64, grid 49x24 ----------
__global__ __launch_bounds__(64)
void k1_fused(const uint16_t* __restrict__ A, const uint16_t* __restrict__ Bcat,
              const float* __restrict__ bmap, uint16_t* __restrict__ mlob,
              uint16_t* __restrict__ gt)
{
    const int lane = threadIdx.x;
    const int quad = lane>>4, lq = lane&15;
    const int row0 = blockIdx.x*32, n0 = blockIdx.y*64;
    const uint16_t* ap[2]; const uint16_t* bp[4];
    #pragma unroll
    for (int i=0;i<2;++i) ap[i] = A    + (size_t)(row0 + i*16 + lq)*NM + quad*8;
    #pragma unroll
    for (int i=0;i<4;++i) bp[i] = Bcat + (size_t)(n0   + i*16 + lq)*NM + quad*8;

    floatx4 acc[8];
    #pragma unroll
    for (int i=0;i<8;++i) acc[i] = (floatx4){0.f,0.f,0.f,0.f};

    short8 Aa[2],Ba[4],Ab[2],Bb[4];
    #pragma unroll
    for (int i=0;i<2;++i) Aa[i]=ldfrag(ap[i]);
    #pragma unroll
    for (int i=0;i<4;++i) Ba[i]=ldfrag(bp[i]);
    #pragma unroll
    for (int i=0;i<2;++i) Ab[i]=ldfrag(ap[i]+32);
    #pragma unroll
    for (int i=0;i<4;++i) Bb[i]=ldfrag(bp[i]+32);

    for (int ks=0; ks<64; ks+=2){
        #pragma unroll
        for (int ms=0;ms<2;++ms)
            #pragma unroll
            for (int ns=0;ns<4;++ns)
                acc[ms*4+ns] = __builtin_amdgcn_mfma_f32_16x16x32_bf16(Aa[ms], Ba[ns], acc[ms*4+ns], 0,0,0);
        if (ks+2 < 64){
            const int off = (ks+2)*32;
            #pragma unroll
            for (int i=0;i<2;++i) Aa[i]=ldfrag(ap[i]+off);
            #pragma unroll
            for (int i=0;i<4;++i) Ba[i]=ldfrag(bp[i]+off);
        }
        #pragma unroll
        for (int ms=0;ms<2;++ms)
            #pragma unroll
            for (int ns=0;ns<4;++ns)
                acc[ms*4+ns] = __builtin_amdgcn_mfma_f32_16x16x32_bf16(Ab[ms], Bb[ns], acc[ms*4+ns], 0,0,0);
        if (ks+3 < 64){
            const int off = (ks+3)*32;
            #pragma unroll
            for (int i=0;i<2;++i) Ab[i]=ldfrag(ap[i]+off);
            #pragma unroll
            for (int i=0;i<4;++i) Bb[i]=ldfrag(bp[i]+off);
        }
    }
    // C/D: col = n0+ns*16+lq, row = row0+ms*16+quad*4+r   (verified R6)
    if (n0 < NH){
        #pragma unroll
        for (int ns=0;ns<4;++ns){
            const int col = n0 + ns*16 + lq;
            const float bv = bmap[col];
            #pragma unroll
            for (int ms=0;ms<2;++ms){
                floatx4 c = acc[ms*4+ns];
                const int rb = row0 + ms*16 + quad*4;
                #pragma unroll
                for (int r=0;r<4;++r)
                    mlob[(size_t)(rb+r)*NH + col] = f2b_(c[r] + bv);
            }
        }
    } else {
        #pragma unroll
        for (int ns=0;ns<4;++ns){
            const int h = n0 - NH + ns*16 + lq;
            #pragma unroll
            for (int ms=0;ms<2;++ms){
                floatx4 c = acc[ms*4+ns];
                const int rb = row0 + ms*16 + quad*4;
                #pragma unroll
                for (int r=0;r<4;++r){
                    const int row = rb + r;
                    const int b = row / NP, p = row - b*NP;
                    gt[((size_t)b*NH + h)*PPAD + p] = f2b_(c[r]);
                }
            }
        }
    }
}

// ---------- K2': scores + softmax. Block per (b,t); thread owns p ----------
__global__ __launch_bounds__(256)
void k2_fused(const uint16_t* __restrict__ mlob, const float* __restrict__ hid,
              const float* __restrict__ Wrect,
              float* __restrict__ attn_out, uint16_t* __restrict__ attnb)
{
    __shared__ uint16_t s_mlo[NP*130];   // 128-h tile, stride 130 (b32 2-way bank = free)
    __shared__ float s_red[8];
    const int bt  = blockIdx.x;          // b*64 + t
    const int b   = bt >> 6;
    const int tid = threadIdx.x;
    const int lane = tid & 63, wave = tid >> 6;
    const float* hrow = hid + (size_t)bt*NH;

    float score = 0.f;
    for (int kt=0; kt<6; ++kt){
        __syncthreads();
        // stage mlo[b, :, kt*128 .. +128): NP rows x 64 uint32 chunks
        for (int idx=tid; idx<NP*64; idx+=256){
            const int p = idx >> 6, j = idx & 63;       // FIX R8: was >>5/&31 (LDS OOB)
            *(uint32_t*)&s_mlo[p*130 + j*2] =
                *(const uint32_t*)&mlob[((size_t)b*NP + p)*NH + kt*128 + j*2];
        }
        __syncthreads();
        if (tid < NP){
            const uint16_t* mp = &s_mlo[tid*130];
            #pragma unroll 8
            for (int c=0; c<128; c+=2){
                const int h = kt*128 + c;
                const float h0 = hrow[h],  h1 = hrow[h+1];      // uniform -> SGPR
                const float w0 = Wrect[h], w1 = Wrect[h+1];
                const uint32_t mm = *(const uint32_t*)(mp + c);
                score = fmaf(fmaxf(lo2f_(mm) + h0, 0.f), w0, score);
                score = fmaf(fmaxf(hi2f_(mm) + h1, 0.f), w1, score);
            }
        }
    }
    // block softmax over p (softmax(x + b_rect) == softmax(x): b_rect drops out)
    float v = (tid < NP) ? score : -3.0e38f;
    #pragma unroll
    for (int off=32; off>0; off>>=1) v = fmaxf(v, __shfl_xor(v, off));
    if (lane == 0) s_red[wave] = v;
    __syncthreads();
    const float mx = fmaxf(fmaxf(s_red[0], s_red[1]), fmaxf(s_red[2], s_red[3]));
    float e = (tid < NP) ? __expf(score - mx) : 0.f;
    float s = e;
    #pragma unroll
    for (int off=32; off>0; off>>=1) s += __shfl_xor(s, off);
    if (lane == 0) s_red[4 + wave] = s;
    __syncthreads();
    const float inv = 1.f / (s_red[4] + s_red[5] + s_red[6] + s_red[7]);
    const float a = e * inv;
    if (tid < NP)   attn_out[(size_t)bt*NP + tid] = a;
    if (tid < PPAD) attnb[(size_t)bt*PPAD + tid] = (tid < NP) ? f2b_(a) : (uint16_t)0;
}

// ---------- K4': out[b,t,:] = attn[b,t,:]·G[b] + bfin + hid. Wave-tile 16x64, K=224 ----------
__global__ __launch_bounds__(64)
void k4_small(const uint16_t* __restrict__ attnb, const uint16_t* __restrict__ gt,
              const float* __restrict__ bfin, const float* __restrict__ hid,
              float* __restrict__ out)
{
    const int lane = threadIdx.x;
    const int quad = lane>>4, lq = lane&15;
    const int tt = blockIdx.x;           // t-tile (4)
    const int n0 = blockIdx.y*64;        // h-tile (12)
    const int b  = blockIdx.z;           // batch (8)
    const uint16_t* aprow = attnb + ((size_t)b*NT + tt*16 + lq)*PPAD + quad*8;
    const uint16_t* bp[4];
    #pragma unroll
    for (int i=0;i<4;++i) bp[i] = gt + ((size_t)b*NH + n0 + i*16 + lq)*PPAD + quad*8;

    floatx4 acc[4];
    #pragma unroll
    for (int i=0;i<4;++i) acc[i] = (floatx4){0.f,0.f,0.f,0.f};
    #pragma unroll
    for (int ks=0; ks<7; ++ks){
        short8 Af = ldfrag(aprow + ks*32);
        #pragma unroll
        for (int i=0;i<4;++i)
            acc[i] = __builtin_amdgcn_mfma_f32_16x16x32_bf16(Af, ldfrag(bp[i] + ks*32), acc[i], 0,0,0);
    }
    #pragma unroll
    for (int ns=0;ns<4;++ns){
        const int col = n0 + ns*16 + lq;
        const float bv = bfin[col];
        floatx4 c = acc[ns];
        #pragma unroll
        for (int r=0;r<4;++r){
            const int row = b*NT + tt*16 + quad*4 + r;
            const size_t idx = (size_t)row*NH + col;
            out[idx] = c[r] + bv + hid[idx];
        }
    }
}

// =================== fallback (R5-proven fp32 path) ===================
__global__ __launch_bounds__(256)
void k1_map(const float* __restrict__ fm, const float* __restrict__ Wmap,
            const float* __restrict__ bmap, float* __restrict__ mlo)
{
    __shared__ float s_fm[8][NM];
    const int row0 = blockIdx.x*8;
    for (int i=threadIdx.x; i<8*NM; i+=256){
        int r=i>>11, k=i&2047;
        s_fm[r][k] = fm[(size_t)(row0+r)*NM + k];
    }
    __syncthreads();
    #pragma unroll
    for (int it=0; it<3; ++it){
        int c = threadIdx.x + it*256;
        float acc[8];
        #pragma unroll
        for(int r=0;r<8;++r) acc[r]=0.f;
        const float* wr = Wmap + (size_t)c*NM;
        for (int k=0;k<NM;k+=4){
            float4 w4 = *(const float4*)(wr + k);
            #pragma unroll
            for(int r=0;r<8;++r){
                acc[r]=fmaf(w4.x,s_fm[r][k+0],acc[r]);
                acc[r]=fmaf(w4.y,s_fm[r][k+1],acc[r]);
                acc[r]=fmaf(w4.z,s_fm[r][k+2],acc[r]);
                acc[r]=fmaf(w4.w,s_fm[r][k+3],acc[r]);
            }
        }
        float bb = bmap[c];
        for(int r=0;r<8;++r) mlo[(size_t)(row0+r)*NH + c] = acc[r]+bb;
    }
}

__global__ __launch_bounds__(256)
void k2_scores_f(const float* __restrict__ mlo, const float* __restrict__ hid,
                 const float* __restrict__ Wrect, const float* __restrict__ brect,
                 float* __restrict__ attn_out)
{
    const int b    = blockIdx.x >> 4;
    const int tg   = blockIdx.x & 15;
    const int wave = threadIdx.x >> 6;
    const int lane = threadIdx.x & 63;
    const int t    = tg*4 + wave;
    float hv[12], wv[12];
    #pragma unroll
    for (int j=0;j<12;++j){
        int h = lane + 64*j;
        hv[j] = hid[(size_t)(b*NT+t)*NH + h];
        wv[j] = Wrect[h];
    }
    __shared__ float s_sc[4][NP];
    for (int p=0;p<NP;++p){
        const float* mr = mlo + ((size_t)b*NP + p)*NH;
        float acc = 0.f;
        #pragma unroll
        for (int j=0;j<12;++j){
            float v = fmaxf(mr[lane+64*j] + hv[j], 0.f);
            acc = fmaf(v,wv[j],acc);
        }
        #pragma unroll
        for (int off=32; off>0; off>>=1) acc += __shfl_down(acc,off);
        if (lane==0) s_sc[wave][p] = acc;
    }
    __syncthreads();
    float x[4]; int pidx[4];
    #pragma unroll
    for (int i=0;i<4;++i){
        int p = lane + 64*i; pidx[i]=p;
        x[i] = (p<NP) ? s_sc[wave][p] : -3.0e38f;
    }
    float mx = fmaxf(fmaxf(x[0],x[1]),fmaxf(x[2],x[3]));
    #pragma unroll
    for (int off=32; off>0; off>>=1) mx = fmaxf(mx,__shfl_xor(mx,off));
    float sum=0.f;
    #pragma unroll
    for (int i=0;i<4;++i){ x[i] = (pidx[i]<NP) ? __expf(x[i]-mx) : 0.f; sum += x[i]; }
    #pragma unroll
    for (int off=32; off>0; off>>=1) sum += __shfl_xor(sum,off);
    const float inv = 1.f/sum;
    const size_t base = (size_t)(b*NT+t)*NP;
    #pragma unroll
    for (int i=0;i<4;++i) if (pidx[i]<NP) attn_out[base+pidx[i]] = x[i]*inv;
}

__global__ __launch_bounds__(256)
void k3_ctx(const float* __restrict__ attn, const float* __restrict__ fm,
            float* __restrict__ ctx)
{
    const int b  = blockIdx.x >> 4;
    const int tg = blockIdx.x & 15;
    __shared__ float s_a[4][NP];
    for (int i=threadIdx.x; i<4*NP; i+=256){
        int tt=i/NP, p=i-tt*NP;
        s_a[tt][p] = attn[(size_t)(b*NT + tg*4+tt)*NP + p];
    }
    __syncthreads();
    const int m0 = threadIdx.x*8;
    float acc[4][8];
    #pragma unroll
    for(int tt=0;tt<4;++tt)
        #pragma unroll
        for(int i=0;i<8;++i) acc[tt][i]=0.f;
    const float* fb = fm + (size_t)b*NP*NM + m0;
    for (int p=0;p<NP;++p){
        float4 u0 = *(const float4*)(fb + (size_t)p*NM);
        float4 u1 = *(const float4*)(fb + (size_t)p*NM + 4);
        float f[8] = {u0.x,u0.y,u0.z,u0.w,u1.x,u1.y,u1.z,u1.w};
        #pragma unroll
        for(int tt=0;tt<4;++tt){
            float a = s_a[tt][p];
            #pragma unroll
            for(int i=0;i<8;++i) acc[tt][i] = fmaf(a,f[i],acc[tt][i]);
        }
    }
    #pragma unroll
    for(int tt=0;tt<4;++tt){
        float* cr = ctx + (size_t)(b*NT + tg*4+tt)*NM + m0;
        #pragma unroll
        for(int i=0;i<8;++i) cr[i]=acc[tt][i];
    }
}

__global__ __launch_bounds__(256)
void k4_final(const float* __restrict__ ctx, const float* __restrict__ Wfin,
              const float* __restrict__ bfin, const float* __restrict__ hid,
              float* __restrict__ out)
{
    __shared__ float s_c[8][NM];
    const int row0 = blockIdx.x*8;
    for (int i=threadIdx.x; i<8*NM; i+=256){
        int r=i>>11, k=i&2047;
        s_c[r][k] = ctx[(size_t)(row0+r)*NM + k];
    }
    __syncthreads();
    #pragma unroll
    for (int it=0; it<3; ++it){
        int c = threadIdx.x + it*256;
        float acc[8];
        #pragma unroll
        for(int r=0;r<8;++r) acc[r]=0.f;
        const float* wr = Wfin + (size_t)c*NM;
        for (int k=0;k<NM;k+=4){
            float4 w4 = *(const float4*)(wr + k);
            #pragma unroll
            for(int r=0;r<8;++r){
                acc[r]=fmaf(w4.x,s_c[r][k+0],acc[r]);
                acc[r]=fmaf(w4.y,s_c[r][k+1],acc[r]);
                acc[r]=fmaf(w4.z,s_c[r][k+2],acc[r]);
                acc[r]=fmaf(w4.w,s_c[r][k+3],acc[r]);
            }
        }
        float bb = bfin[c];
        for(int r=0;r<8;++r)
            out[(size_t)(row0+r)*NH + c] = acc[r] + bb + hid[(size_t)(row0+r)*NH + c];
    }
}

extern "C" void kernel_launch(void* const* d_in, const int* in_sizes, int n_in,
                              void* d_out, int out_size, void* d_ws, size_t ws_size,
                              hipStream_t stream)
{
    const float* maps  = (const float*)d_in[0];
    const float* hid   = (const float*)d_in[1];
    const float* Wmap  = (const float*)d_in[2];
    const float* bmap  = (const float*)d_in[3];
    const float* Wfin  = (const float*)d_in[4];
    const float* bfin  = (const float*)d_in[5];
    const float* Wrect = (const float*)d_in[6];
    const float* brect = (const float*)d_in[7];

    float* out_ptr  = (float*)d_out;                  // (B,T,H) fp32
    float* attn_out = out_ptr + (size_t)NB*NT*NH;     // (B,T,P) fp32

    const int    FME    = NB*NP*NM;                   // 3,211,264
    const int    WE     = NH*NM;                      // 1,572,864
    const size_t fmb_b  = (size_t)FME*2;              // 6,422,528
    const size_t w_b    = (size_t)WE*2;               // 3,145,728 (x2, contiguous => Bcat)
    const size_t mlob_b = (size_t)NB*NP*NH*2;         // 2,408,448
    const size_t gt_b   = (size_t)NB*NH*PPAD*2;       // 2,752,512
    const size_t atb_b  = (size_t)NB*NT*PPAD*2;       //   229,376
    const size_t need   = fmb_b + 2*w_b + mlob_b + gt_b + atb_b;  // ~17.3 MiB

    if (ws_size >= need) {
        uint16_t* fmb   = (uint16_t*)d_ws;
        uint16_t* wcat  = (uint16_t*)((char*)d_ws + fmb_b);          // [Wmap;Wfin] 1536x2048
        uint16_t* wfinb = wcat + (size_t)WE;
        uint16_t* mlob  = (uint16_t*)((char*)d_ws + fmb_b + 2*w_b);
        uint16_t* gt    = mlob + (size_t)NB*NP*NH;
        uint16_t* attnb = gt   + (size_t)NB*NH*PPAD;

        const int total8 = (FME + 2*WE)/8;            // 794,624 -> 3104 blocks
        hipLaunchKernelGGL(cvt3, dim3(total8/256), dim3(256), 0, stream,
                           maps, fmb, FME, Wmap, wcat, WE, Wfin, wfinb, WE);
        hipLaunchKernelGGL(k1_fused, dim3(49,24), dim3(64), 0, stream,
                           fmb, wcat, bmap, mlob, gt);
        hipLaunchKernelGGL(k2_fused, dim3(NB*NT), dim3(256), 0, stream,
                           mlob, hid, Wrect, attn_out, attnb);
        hipLaunchKernelGGL(k4_small, dim3(4,12,NB), dim3(64), 0, stream,
                           attnb, gt, bfin, hid, out_ptr);
    } else {
        // R5-proven fp32 fallback
        float* mlo = (float*)d_ws;
        float* ctx = mlo + (size_t)NB*NP*NH;
        hipLaunchKernelGGL(k1_map,     dim3(NB*NP/8),   dim3(256), 0, stream, maps, Wmap, bmap, mlo);
        hipLaunchKernelGGL(k2_scores_f,dim3(NB*(NT/4)), dim3(256), 0, stream, mlo, hid, Wrect, brect, attn_out);
        hipLaunchKernelGGL(k3_ctx,     dim3(NB*(NT/4)), dim3(256), 0, stream, attn_out, maps, ctx);
        hipLaunchKernelGGL(k4_final,   dim3(NB*NT/8),   dim3(256), 0, stream, ctx, Wfin, bfin, hid, out_ptr);
    }
}

// Round 9
// 166.761 us; speedup vs baseline: 4.0196x; 1.1845x over previous
//
#include <hip/hip_runtime.h>
#include <stdint.h>

#define NB 8
#define NP 196
#define NM 2048
#define NH 768
#define NT 64
#define PPAD 224          // NP padded to multiple of 32 for MFMA K
#define NROWS (NB*NP)     // 1568

typedef __attribute__((ext_vector_type(8))) short short8;
typedef __attribute__((ext_vector_type(4))) float floatx4;

__device__ __forceinline__ float lo2f_(uint32_t u){ union{uint32_t i; float f;} v; v.i=u<<16; return v.f; }
__device__ __forceinline__ float hi2f_(uint32_t u){ union{uint32_t i; float f;} v; v.i=u&0xffff0000u; return v.f; }
__device__ __forceinline__ uint16_t f2b_(float f){
    union{float f; uint32_t i;} v; v.f=f; uint32_t x=v.i;
    return (uint16_t)((x + 0x7fffu + ((x>>16)&1u))>>16);
}
__device__ __forceinline__ short8 u4_to_s8(uint4 u){
    union{ uint4 u; short8 s; } v; v.u = u; return v.s;
}
__device__ __forceinline__ short8 ldsfrag(const uint16_t* p){
    union{ uint4 u; short8 s; } v; v.u = *(const uint4*)p; return v.s;
}

// ---------- cvt3: fp32 -> bf16 for maps, W_map, W_final ----------
__global__ __launch_bounds__(256)
void cvt3(const float* __restrict__ s0, uint16_t* __restrict__ d0, int n0,
          const float* __restrict__ s1, uint16_t* __restrict__ d1, int n1,
          const float* __restrict__ s2, uint16_t* __restrict__ d2, int n2)
{
    long i = (long)(blockIdx.x*256 + threadIdx.x)*8;
    const float* s; uint16_t* d; long j;
    if (i < n0)                { s=s0; d=d0; j=i; }
    else if (i < (long)n0+n1)  { s=s1; d=d1; j=i-n0; }
    else                       { s=s2; d=d2; j=i-n0-n1; if (j>=n2) return; }
    float4 a = *(const float4*)(s+j);
    float4 b = *(const float4*)(s+j+4);
    uint4 w;
    w.x = (uint32_t)f2b_(a.x) | ((uint32_t)f2b_(a.y)<<16);
    w.y = (uint32_t)f2b_(a.z) | ((uint32_t)f2b_(a.w)<<16);
    w.z = (uint32_t)f2b_(b.x) | ((uint32_t)f2b_(b.y)<<16);
    w.w = (uint32_t)f2b_(b.z) | ((uint32_t)f2b_(b.w)<<16);
    *(uint4*)(d+j) = w;
}

// ---------- K1 (LDS-tiled MFMA): [mlo | G] = fm · [Wmap;Wfin]^T ----------
// 64x64 block tile, BK=64, 256 thr (4 waves, each 32x32). Grid (25, 24).
#define LSTR 72           // LDS row stride in elems (pad 64->72: b128 2-way max)
__global__ __launch_bounds__(256)
void k1_tiled(const uint16_t* __restrict__ A, const uint16_t* __restrict__ Bcat,
              const float* __restrict__ bmap, uint16_t* __restrict__ mlob,
              uint16_t* __restrict__ gt)
{
    __shared__ uint16_t sA[64*LSTR];
    __shared__ uint16_t sB[64*LSTR];
    const int tid  = threadIdx.x;
    const int wv   = tid >> 6, lane = tid & 63;
    const int quad = lane >> 4, lq = lane & 15;
    const int m0 = blockIdx.x*64, n0 = blockIdx.y*64;

    // staging: chunk c -> row r=c>>3, k-chunk q=c&7 (16B each). thread owns c=tid, c=tid+256.
    const int r0 = tid >> 3, q0 = tid & 7;
    const int r1 = r0 + 32;
    int gar0 = m0 + r0; if (gar0 >= NROWS) gar0 = NROWS-1;
    int gar1 = m0 + r1; if (gar1 >= NROWS) gar1 = NROWS-1;
    const uint16_t* pa0 = A + (size_t)gar0*NM + q0*8;
    const uint16_t* pa1 = A + (size_t)gar1*NM + q0*8;
    const uint16_t* pb0 = Bcat + (size_t)(n0 + r0)*NM + q0*8;
    const uint16_t* pb1 = Bcat + (size_t)(n0 + r1)*NM + q0*8;
    uint16_t* la0 = &sA[r0*LSTR + q0*8];
    uint16_t* la1 = &sA[r1*LSTR + q0*8];
    uint16_t* lb0 = &sB[r0*LSTR + q0*8];
    uint16_t* lb1 = &sB[r1*LSTR + q0*8];

    const int msub = (wv & 1)*32, nsub = (wv >> 1)*32;

    floatx4 acc[2][2];
    #pragma unroll
    for (int i=0;i<2;++i)
        #pragma unroll
        for (int j=0;j<2;++j) acc[i][j] = (floatx4){0.f,0.f,0.f,0.f};

    uint4 va0 = *(const uint4*)pa0, va1 = *(const uint4*)pa1;
    uint4 vb0 = *(const uint4*)pb0, vb1 = *(const uint4*)pb1;

    for (int ks=0; ks<32; ++ks){
        *(uint4*)la0 = va0; *(uint4*)la1 = va1;
        *(uint4*)lb0 = vb0; *(uint4*)lb1 = vb1;
        __syncthreads();
        if (ks < 31){
            const int off = (ks+1)*64;
            va0 = *(const uint4*)(pa0 + off);
            va1 = *(const uint4*)(pa1 + off);
            vb0 = *(const uint4*)(pb0 + off);
            vb1 = *(const uint4*)(pb1 + off);
        }
        #pragma unroll
        for (int kk=0; kk<2; ++kk){
            short8 af[2], bf[2];
            #pragma unroll
            for (int mt=0;mt<2;++mt)
                af[mt] = ldsfrag(&sA[(msub + mt*16 + lq)*LSTR + kk*32 + quad*8]);
            #pragma unroll
            for (int nt=0;nt<2;++nt)
                bf[nt] = ldsfrag(&sB[(nsub + nt*16 + lq)*LSTR + kk*32 + quad*8]);
            #pragma unroll
            for (int mt=0;mt<2;++mt)
                #pragma unroll
                for (int nt=0;nt<2;++nt)
                    acc[mt][nt] = __builtin_amdgcn_mfma_f32_16x16x32_bf16(af[mt], bf[nt], acc[mt][nt], 0,0,0);
        }
        __syncthreads();
    }

    // epilogue. C/D: local col = nsub+nt*16+lq, local row = msub+mt*16+quad*4+r
    if (n0 < NH){
        #pragma unroll
        for (int nt=0;nt<2;++nt){
            const int col = n0 + nsub + nt*16 + lq;
            const float bv = bmap[col];
            #pragma unroll
            for (int mt=0;mt<2;++mt){
                floatx4 c = acc[mt][nt];
                const int rb = m0 + msub + mt*16 + quad*4;
                #pragma unroll
                for (int r=0;r<4;++r){
                    const int row = rb + r;
                    if (row < NROWS) mlob[(size_t)row*NH + col] = f2b_(c[r] + bv);
                }
            }
        }
    } else {
        #pragma unroll
        for (int nt=0;nt<2;++nt){
            const int h = n0 - NH + nsub + nt*16 + lq;
            #pragma unroll
            for (int mt=0;mt<2;++mt){
                floatx4 c = acc[mt][nt];
                const int rb = m0 + msub + mt*16 + quad*4;
                #pragma unroll
                for (int r=0;r<4;++r){
                    const int row = rb + r;
                    if (row < NROWS){
                        const int b = row / NP, p = row - b*NP;
                        gt[((size_t)b*NH + h)*PPAD + p] = f2b_(c[r]);
                    }
                }
            }
        }
    }
}

// ---------- K2 v2: scores + softmax. Block per (b,t); thread owns p. ----------
// hid row + Wrect staged in LDS once; mlo in 64-h tiles (stride 66).
__global__ __launch_bounds__(256)
void k2f2(const uint16_t* __restrict__ mlob, const float* __restrict__ hid,
          const float* __restrict__ Wrect,
          float* __restrict__ attn_out, uint16_t* __restrict__ attnb)
{
    __shared__ uint16_t s_mlo[NP*66];    // 25.9 KB
    __shared__ float s_h[NH];            // 3 KB
    __shared__ float s_w[NH];            // 3 KB
    __shared__ float s_red[8];
    const int bt  = blockIdx.x;          // b*64 + t
    const int b   = bt >> 6;
    const int tid = threadIdx.x;
    const int lane = tid & 63, wave = tid >> 6;

    for (int i=tid; i<NH; i+=256){
        s_h[i] = hid[(size_t)bt*NH + i];
        s_w[i] = Wrect[i];
    }

    float score = 0.f;
    for (int kt=0; kt<12; ++kt){
        __syncthreads();                  // first iter: also guards s_h/s_w
        for (int idx=tid; idx<NP*32; idx+=256){
            const int p = idx >> 5, j = idx & 31;
            *(uint32_t*)&s_mlo[p*66 + j*2] =
                *(const uint32_t*)&mlob[((size_t)b*NP + p)*NH + kt*64 + j*2];
        }
        __syncthreads();
        if (tid < NP){
            const uint16_t* mp = &s_mlo[tid*66];
            const float* hh = &s_h[kt*64];
            const float* ww = &s_w[kt*64];
            #pragma unroll
            for (int c=0; c<64; c+=4){
                float4 h4 = *(const float4*)(hh + c);
                float4 w4 = *(const float4*)(ww + c);
                const uint32_t ma = *(const uint32_t*)(mp + c);
                const uint32_t mb = *(const uint32_t*)(mp + c + 2);
                score = fmaf(fmaxf(lo2f_(ma) + h4.x, 0.f), w4.x, score);
                score = fmaf(fmaxf(hi2f_(ma) + h4.y, 0.f), w4.y, score);
                score = fmaf(fmaxf(lo2f_(mb) + h4.z, 0.f), w4.z, score);
                score = fmaf(fmaxf(hi2f_(mb) + h4.w, 0.f), w4.w, score);
            }
        }
    }
    // block softmax over p (b_rect cancels in softmax)
    float v = (tid < NP) ? score : -3.0e38f;
    #pragma unroll
    for (int off=32; off>0; off>>=1) v = fmaxf(v, __shfl_xor(v, off));
    if (lane == 0) s_red[wave] = v;
    __syncthreads();
    const float mx = fmaxf(fmaxf(s_red[0], s_red[1]), fmaxf(s_red[2], s_red[3]));
    float e = (tid < NP) ? __expf(score - mx) : 0.f;
    float s = e;
    #pragma unroll
    for (int off=32; off>0; off>>=1) s += __shfl_xor(s, off);
    if (lane == 0) s_red[4 + wave] = s;
    __syncthreads();
    const float inv = 1.f / (s_red[4] + s_red[5] + s_red[6] + s_red[7]);
    const float a = e * inv;
    if (tid < NP)   attn_out[(size_t)bt*NP + tid] = a;
    if (tid < PPAD) attnb[(size_t)bt*PPAD + tid] = (tid < NP) ? f2b_(a) : (uint16_t)0;
}

// ---------- K4: out[b,t,:] = attn[b,t,:]·G[b] + bfin + hid. Wave-tile 16x64, K=224 ----------
__global__ __launch_bounds__(64)
void k4_small(const uint16_t* __restrict__ attnb, const uint16_t* __restrict__ gt,
              const float* __restrict__ bfin, const float* __restrict__ hid,
              float* __restrict__ out)
{
    const int lane = threadIdx.x;
    const int quad = lane>>4, lq = lane&15;
    const int tt = blockIdx.x;           // t-tile (4)
    const int n0 = blockIdx.y*64;        // h-tile (12)
    const int b  = blockIdx.z;           // batch (8)
    const uint16_t* aprow = attnb + ((size_t)b*NT + tt*16 + lq)*PPAD + quad*8;
    const uint16_t* bp[4];
    #pragma unroll
    for (int i=0;i<4;++i) bp[i] = gt + ((size_t)b*NH + n0 + i*16 + lq)*PPAD + quad*8;

    floatx4 acc[4];
    #pragma unroll
    for (int i=0;i<4;++i) acc[i] = (floatx4){0.f,0.f,0.f,0.f};
    #pragma unroll
    for (int ks=0; ks<7; ++ks){
        short8 Af = ldsfrag(aprow + ks*32);
        #pragma unroll
        for (int i=0;i<4;++i)
            acc[i] = __builtin_amdgcn_mfma_f32_16x16x32_bf16(Af, ldsfrag(bp[i] + ks*32), acc[i], 0,0,0);
    }
    #pragma unroll
    for (int ns=0;ns<4;++ns){
        const int col = n0 + ns*16 + lq;
        const float bv = bfin[col];
        floatx4 c = acc[ns];
        #pragma unroll
        for (int r=0;r<4;++r){
            const int row = b*NT + tt*16 + quad*4 + r;
            const size_t idx = (size_t)row*NH + col;
            out[idx] = c[r] + bv + hid[idx];
        }
    }
}

// =================== fallback (R5-proven fp32 path) ===================
__global__ __launch_bounds__(256)
void k1_map(const float* __restrict__ fm, const float* __restrict__ Wmap,
            const float* __restrict__ bmap, float* __restrict__ mlo)
{
    __shared__ float s_fm[8][NM];
    const int row0 = blockIdx.x*8;
    for (int i=threadIdx.x; i<8*NM; i+=256){
        int r=i>>11, k=i&2047;
        s_fm[r][k] = fm[(size_t)(row0+r)*NM + k];
    }
    __syncthreads();
    #pragma unroll
    for (int it=0; it<3; ++it){
        int c = threadIdx.x + it*256;
        float acc[8];
        #pragma unroll
        for(int r=0;r<8;++r) acc[r]=0.f;
        const float* wr = Wmap + (size_t)c*NM;
        for (int k=0;k<NM;k+=4){
            float4 w4 = *(const float4*)(wr + k);
            #pragma unroll
            for(int r=0;r<8;++r){
                acc[r]=fmaf(w4.x,s_fm[r][k+0],acc[r]);
                acc[r]=fmaf(w4.y,s_fm[r][k+1],acc[r]);
                acc[r]=fmaf(w4.z,s_fm[r][k+2],acc[r]);
                acc[r]=fmaf(w4.w,s_fm[r][k+3],acc[r]);
            }
        }
        float bb = bmap[c];
        for(int r=0;r<8;++r) mlo[(size_t)(row0+r)*NH + c] = acc[r]+bb;
    }
}

__global__ __launch_bounds__(256)
void k2_scores_f(const float* __restrict__ mlo, const float* __restrict__ hid,
                 const float* __restrict__ Wrect, const float* __restrict__ brect,
                 float* __restrict__ attn_out)
{
    const int b    = blockIdx.x >> 4;
    const int tg   = blockIdx.x & 15;
    const int wave = threadIdx.x >> 6;
    const int lane = threadIdx.x & 63;
    const int t    = tg*4 + wave;
    float hv[12], wv[12];
    #pragma unroll
    for (int j=0;j<12;++j){
        int h = lane + 64*j;
        hv[j] = hid[(size_t)(b*NT+t)*NH + h];
        wv[j] = Wrect[h];
    }
    __shared__ float s_sc[4][NP];
    for (int p=0;p<NP;++p){
        const float* mr = mlo + ((size_t)b*NP + p)*NH;
        float acc = 0.f;
        #pragma unroll
        for (int j=0;j<12;++j){
            float v = fmaxf(mr[lane+64*j] + hv[j], 0.f);
            acc = fmaf(v,wv[j],acc);
        }
        #pragma unroll
        for (int off=32; off>0; off>>=1) acc += __shfl_down(acc,off);
        if (lane==0) s_sc[wave][p] = acc;
    }
    __syncthreads();
    float x[4]; int pidx[4];
    #pragma unroll
    for (int i=0;i<4;++i){
        int p = lane + 64*i; pidx[i]=p;
        x[i] = (p<NP) ? s_sc[wave][p] : -3.0e38f;
    }
    float mx = fmaxf(fmaxf(x[0],x[1]),fmaxf(x[2],x[3]));
    #pragma unroll
    for (int off=32; off>0; off>>=1) mx = fmaxf(mx,__shfl_xor(mx,off));
    float sum=0.f;
    #pragma unroll
    for (int i=0;i<4;++i){ x[i] = (pidx[i]<NP) ? __expf(x[i]-mx) : 0.f; sum += x[i]; }
    #pragma unroll
    for (int off=32; off>0; off>>=1) sum += __shfl_xor(sum,off);
    const float inv = 1.f/sum;
    const size_t base = (size_t)(b*NT+t)*NP;
    #pragma unroll
    for (int i=0;i<4;++i) if (pidx[i]<NP) attn_out[base+pidx[i]] = x[i]*inv;
}

__global__ __launch_bounds__(256)
void k3_ctx(const float* __restrict__ attn, const float* __restrict__ fm,
            float* __restrict__ ctx)
{
    const int b  = blockIdx.x >> 4;
    const int tg = blockIdx.x & 15;
    __shared__ float s_a[4][NP];
    for (int i=threadIdx.x; i<4*NP; i+=256){
        int tt=i/NP, p=i-tt*NP;
        s_a[tt][p] = attn[(size_t)(b*NT + tg*4+tt)*NP + p];
    }
    __syncthreads();
    const int m0 = threadIdx.x*8;
    float acc[4][8];
    #pragma unroll
    for(int tt=0;tt<4;++tt)
        #pragma unroll
        for(int i=0;i<8;++i) acc[tt][i]=0.f;
    const float* fb = fm + (size_t)b*NP*NM + m0;
    for (int p=0;p<NP;++p){
        float4 u0 = *(const float4*)(fb + (size_t)p*NM);
        float4 u1 = *(const float4*)(fb + (size_t)p*NM + 4);
        float f[8] = {u0.x,u0.y,u0.z,u0.w,u1.x,u1.y,u1.z,u1.w};
        #pragma unroll
        for(int tt=0;tt<4;++tt){
            float a = s_a[tt][p];
            #pragma unroll
            for(int i=0;i<8;++i) acc[tt][i] = fmaf(a,f[i],acc[tt][i]);
        }
    }
    #pragma unroll
    for(int tt=0;tt<4;++tt){
        float* cr = ctx + (size_t)(b*NT + tg*4+tt)*NM + m0;
        #pragma unroll
        for(int i=0;i<8;++i) cr[i]=acc[tt][i];
    }
}

__global__ __launch_bounds__(256)
void k4_final(const float* __restrict__ ctx, const float* __restrict__ Wfin,
              const float* __restrict__ bfin, const float* __restrict__ hid,
              float* __restrict__ out)
{
    __shared__ float s_c[8][NM];
    const int row0 = blockIdx.x*8;
    for (int i=threadIdx.x; i<8*NM; i+=256){
        int r=i>>11, k=i&2047;
        s_c[r][k] = ctx[(size_t)(row0+r)*NM + k];
    }
    __syncthreads();
    #pragma unroll
    for (int it=0; it<3; ++it){
        int c = threadIdx.x + it*256;
        float acc[8];
        #pragma unroll
        for(int r=0;r<8;++r) acc[r]=0.f;
        const float* wr = Wfin + (size_t)c*NM;
        for (int k=0;k<NM;k+=4){
            float4 w4 = *(const float4*)(wr + k);
            #pragma unroll
            for(int r=0;r<8;++r){
                acc[r]=fmaf(w4.x,s_c[r][k+0],acc[r]);
                acc[r]=fmaf(w4.y,s_c[r][k+1],acc[r]);
                acc[r]=fmaf(w4.z,s_c[r][k+2],acc[r]);
                acc[r]=fmaf(w4.w,s_c[r][k+3],acc[r]);
            }
        }
        float bb = bfin[c];
        for(int r=0;r<8;++r)
            out[(size_t)(row0+r)*NH + c] = acc[r] + bb + hid[(size_t)(row0+r)*NH + c];
    }
}

extern "C" void kernel_launch(void* const* d_in, const int* in_sizes, int n_in,
                              void* d_out, int out_size, void* d_ws, size_t ws_size,
                              hipStream_t stream)
{
    const float* maps  = (const float*)d_in[0];
    const float* hid   = (const float*)d_in[1];
    const float* Wmap  = (const float*)d_in[2];
    const float* bmap  = (const float*)d_in[3];
    const float* Wfin  = (const float*)d_in[4];
    const float* bfin  = (const float*)d_in[5];
    const float* Wrect = (const float*)d_in[6];
    const float* brect = (const float*)d_in[7];

    float* out_ptr  = (float*)d_out;                  // (B,T,H) fp32
    float* attn_out = out_ptr + (size_t)NB*NT*NH;     // (B,T,P) fp32

    const int    FME    = NB*NP*NM;                   // 3,211,264
    const int    WE     = NH*NM;                      // 1,572,864
    const size_t fmb_b  = (size_t)FME*2;
    const size_t w_b    = (size_t)WE*2;
    const size_t mlob_b = (size_t)NB*NP*NH*2;
    const size_t gt_b   = (size_t)NB*NH*PPAD*2;
    const size_t atb_b  = (size_t)NB*NT*PPAD*2;
    const size_t need   = fmb_b + 2*w_b + mlob_b + gt_b + atb_b;  // ~17.3 MiB

    if (ws_size >= need) {
        uint16_t* fmb   = (uint16_t*)d_ws;
        uint16_t* wcat  = (uint16_t*)((char*)d_ws + fmb_b);          // [Wmap;Wfin] 1536x2048
        uint16_t* wfinb = wcat + (size_t)WE;
        uint16_t* mlob  = (uint16_t*)((char*)d_ws + fmb_b + 2*w_b);
        uint16_t* gt    = mlob + (size_t)NB*NP*NH;
        uint16_t* attnb = gt   + (size_t)NB*NH*PPAD;

        const int total8 = (FME + 2*WE)/8;
        hipLaunchKernelGGL(cvt3, dim3(total8/256), dim3(256), 0, stream,
                           maps, fmb, FME, Wmap, wcat, WE, Wfin, wfinb, WE);
        hipLaunchKernelGGL(k1_tiled, dim3(25,24), dim3(256), 0, stream,
                           fmb, wcat, bmap, mlob, gt);
        hipLaunchKernelGGL(k2f2, dim3(NB*NT), dim3(256), 0, stream,
                           mlob, hid, Wrect, attn_out, attnb);
        hipLaunchKernelGGL(k4_small, dim3(4,12,NB), dim3(64), 0, stream,
                           attnb, gt, bfin, hid, out_ptr);
    } else {
        // R5-proven fp32 fallback
        float* mlo = (float*)d_ws;
        float* ctx = mlo + (size_t)NB*NP*NH;
        hipLaunchKernelGGL(k1_map,     dim3(NB*NP/8),   dim3(256), 0, stream, maps, Wmap, bmap, mlo);
        hipLaunchKernelGGL(k2_scores_f,dim3(NB*(NT/4)), dim3(256), 0, stream, mlo, hid, Wrect, brect, attn_out);
        hipLaunchKernelGGL(k3_ctx,     dim3(NB*(NT/4)), dim3(256), 0, stream, attn_out, maps, ctx);
        hipLaunchKernelGGL(k4_final,   dim3(NB*NT/8),   dim3(256), 0, stream, ctx, Wfin, bfin, hid, out_ptr);
    }
}